// Round 6
// baseline (271.637 us; speedup 1.0000x reference)
//
#include <hip/hip_runtime.h>
#include <cstddef>

// Swin shifted-window attention, fused per-window MFMA kernel, fp16, v6.
// v5 + (a) transposed QKV projection: Q^T/K^T = W*X^T so the D-fragment matches
// the LDS fragment layout -> all scatter is b64 (kills ~300 scalar-write VALU/wave);
// wave owns one m-tile (x loads 24->6 b128); (b) exp2-domain softmax (log2e folded
// into q-scale and bias at prep); (c) ring-3 weight prefetch; (d) next-head
// operand prefetch in phase 2.
// 8192 windows, one per 256-thread block (4 waves); LDS 40960 B -> 4 blocks/CU.

typedef _Float16 half8 __attribute__((ext_vector_type(8)));
typedef float f4v __attribute__((ext_vector_type(4)));
typedef unsigned short u16;
typedef unsigned int u32;

#define MFMA(A, B, C) __builtin_amdgcn_mfma_f32_16x16x32_f16((A), (B), (C), 0, 0, 0)

__device__ inline u16 f16b(float f) { return __builtin_bit_cast(u16, (_Float16)f); }
__device__ inline u32 pkrtz(float a, float b) {
    return __builtin_bit_cast(u32, __builtin_amdgcn_cvt_pkrtz(a, b));
}
// fragment-LDS unit swizzle: byte = frag*1024 + unit*16 + elem*2
__device__ inline int SWU(int a, int kg) {
    return (((a ^ (kg << 1) ^ ((a & 8) >> 1)) & 15) | (kg << 4));
}

// ---- prep: weights -> f16 (q rows pre-scaled by SCALE*log2e), bias matrix *log2e ----
__global__ void prep_kernel(const float* __restrict__ wqkv, const float* __restrict__ wout,
                            const float* __restrict__ btab, const int* __restrict__ ridx,
                            const float* __restrict__ bqkv,
                            u16* __restrict__ wq16, u16* __restrict__ wo16,
                            float* __restrict__ bmat, float* __restrict__ bqs)
{
    const int i = blockIdx.x * 256 + threadIdx.x;
    const float QS = 0.17677669529663688f * 1.4426950408889634f;  // 1/sqrt(32) * log2(e)
    if (i < 27648) {
        float f = wqkv[i];
        if (i < 9216) f *= QS;                 // q rows (0..95)
        wq16[i] = f16b(f);
    } else if (i < 36864) {
        wo16[i - 27648] = f16b(wout[i - 27648]);
    } else if (i < 49152) {
        const int j = i - 36864;               // [3][64][64]
        const int h = j >> 12, rem = j & 4095, r = rem >> 6, u = rem & 63;
        bmat[j] = (r < 49 && u < 49) ? btab[ridx[r * 49 + u] * 3 + h] * 1.4426950408889634f : 0.f;
    } else if (i < 49440) {
        const int j = i - 49152;
        float f = bqkv[j];
        if (j < 96) f *= QS;
        bqs[j] = f;
    }
}

// ---- main fused kernel ----
__global__ __launch_bounds__(256, 4)
void swin_kernel(const float* __restrict__ x,
                 const u16* __restrict__ wq16,
                 const u16* __restrict__ wo16,
                 const float* __restrict__ bqs,
                 const float* __restrict__ bout,
                 const float* __restrict__ bm,
                 float* __restrict__ out)
{
    // LDS map (40960 B -> 4 blocks/CU):
    //   QT [0,12288)      qt frag(h*4+m); reused per head as pt-ku0[m], then aot(h*4+m)
    //   KT [12288,24576)  kt frag(h*4+ut)
    //   VT [24576,36864)  vt frag((h*2+nd)*2+ku)
    //   PL [36864,40960)  pt-ku1, 1KB per wave
    __shared__ __attribute__((aligned(16))) char smem[40960];
    constexpr int QT = 0, KT = 12288, VT = 24576, PL = 36864;

    const int tid  = threadIdx.x;
    const int w    = tid >> 6;        // wave 0..3 = token m-tile owned
    const int lane = tid & 63;
    const int l15  = lane & 15;
    const int lg   = lane >> 4;       // 0..3

    const int blk = blockIdx.x;
    const int bb  = blk >> 10;
    const int wi7 = ((blk >> 5) & 31) * 7;
    const int wj7 = (blk & 31) * 7;

    const int swbase = SWU(l15, lg) * 16;
    const int elb    = ((lg & 1) * 4) * 2;    // byte offset of el0 within unit

    // ============ Phase 1: QKV projection ============
    // xb = X^T B-frag for tokens t = w*16 + l15 (dual-use as A-frag for V path).
    half8 xb[3];
    {
        const int t = w * 16 + l15;           // t in [0,64): t>=49 reads junk (masked later)
        const int tr = t / 7, tc = t - tr * 7;
        int r = wi7 + tr + 3; if (r >= 224) r -= 224;
        int c = wj7 + tc + 3; if (c >= 224) c -= 224;
        const float* xrow = x + ((size_t)((bb * 224 + r) * 224 + c)) * 96 + lg * 8;
        #pragma unroll
        for (int ks = 0; ks < 3; ++ks) {
            const float4 f0 = *(const float4*)(xrow + ks * 32);
            const float4 f1 = *(const float4*)(xrow + ks * 32 + 4);
            uint4 pk;
            pk.x = pkrtz(f0.x, f0.y); pk.y = pkrtz(f0.z, f0.w);
            pk.z = pkrtz(f1.x, f1.y); pk.w = pkrtz(f1.z, f1.w);
            xb[ks] = __builtin_bit_cast(half8, pk);
        }
    }
    {
        const u16* wbase = wq16 + (size_t)l15 * 96 + lg * 8;
        half8 wf[3][3];                        // ring-3 weight prefetch
        #pragma unroll
        for (int s3 = 0; s3 < 3; ++s3) {
            const u16* p = wbase + s3 * 1536;
            wf[s3][0] = *(const half8*)(p);
            wf[s3][1] = *(const half8*)(p + 32);
            wf[s3][2] = *(const half8*)(p + 64);
        }
        #pragma unroll
        for (int n = 0; n < 18; ++n) {
            const int cs = n % 3;
            f4v acc = {0.f, 0.f, 0.f, 0.f};
            if (n < 12) {                      // q/k: transposed (A=W, B=X^T)
                acc = MFMA(wf[cs][0], xb[0], acc);
                acc = MFMA(wf[cs][1], xb[1], acc);
                acc = MFMA(wf[cs][2], xb[2], acc);
            } else {                           // v: direct (A=X, B=W^T) - same regs
                acc = MFMA(xb[0], wf[cs][0], acc);
                acc = MFMA(xb[1], wf[cs][1], acc);
                acc = MFMA(xb[2], wf[cs][2], acc);
            }
            if (n < 15) {                      // refill ring slot just consumed
                const u16* p = wbase + (n + 3) * 1536;
                wf[cs][0] = *(const half8*)(p);
                wf[cs][1] = *(const half8*)(p + 32);
                wf[cs][2] = *(const half8*)(p + 64);
            }
            if (n < 12) {
                // D[oc = n*16+lg*4+i][tok = w*16+l15]: 4 consecutive channels/thread
                const float4 b4 = *(const float4*)(bqs + n * 16 + lg * 4);
                uint2 pv;
                pv.x = pkrtz(acc[0] + b4.x, acc[1] + b4.y);
                pv.y = pkrtz(acc[2] + b4.z, acc[3] + b4.w);
                char* dst = smem + ((n < 6) ? (QT + (((n >> 1) * 4 + w) << 10))
                                            : (KT + ((((n - 6) >> 1) * 4 + w) << 10)));
                const int kg = ((n & 1) << 1) + (lg >> 1);
                *(uint2*)(dst + SWU(l15, kg) * 16 + elb) = pv;
            } else {
                // D[tok = w*16+lg*4+i][oc = n*16+l15]: 4 consecutive tokens/thread
                const float bv = bqs[n * 16 + l15];
                uint2 pv;
                pv.x = pkrtz(acc[0] + bv, acc[1] + bv);
                pv.y = pkrtz(acc[2] + bv, acc[3] + bv);
                const int h = (n - 12) >> 1, nd = n & 1;
                const int kg = ((w & 1) << 1) + (lg >> 1);
                *(uint2*)(smem + VT + (((h * 2 + nd) * 2 + (w >> 1)) << 10) +
                          SWU(l15, kg) * 16 + elb) = pv;
            }
        }
    }
    __syncthreads();

    // ============ Phase 2: attention, zero barriers (exp2 domain) ============
    {
        const int t = w * 16 + l15;
        half8 qa = *(const half8*)(smem + QT + ((0 * 4 + w) << 10) + swbase);
        half8 kb[4];
        #pragma unroll
        for (int ut = 0; ut < 4; ++ut)
            kb[ut] = *(const half8*)(smem + KT + ((0 * 4 + ut) << 10) + swbase);

        #pragma unroll
        for (int h = 0; h < 3; ++h) {
            const int qfr = QT + ((h * 4 + w) << 10);
            f4v s[4];
            #pragma unroll
            for (int ut = 0; ut < 4; ++ut) {
                f4v z = {0.f, 0.f, 0.f, 0.f};
                s[ut] = MFMA(kb[ut], qa, z);   // D[u-rows][t-cols], log2-scaled
            }
            // prefetch next head's operands (their frags are untouched this head)
            half8 qan; half8 kbn[4];
            if (h < 2) {
                qan = *(const half8*)(smem + QT + (((h + 1) * 4 + w) << 10) + swbase);
                #pragma unroll
                for (int ut = 0; ut < 4; ++ut)
                    kbn[ut] = *(const half8*)(smem + KT + (((h + 1) * 4 + ut) << 10) + swbase);
            }
            // + relative position bias (pre-scaled by log2e)
            const float* bp = bm + h * 4096 + t * 64 + lg * 4;
            #pragma unroll
            for (int ut = 0; ut < 4; ++ut) {
                const float4 bv = *(const float4*)(bp + ut * 16);
                s[ut][0] += bv.x; s[ut][1] += bv.y; s[ut][2] += bv.z; s[ut][3] += bv.w;
            }
            // mask u >= 49 (ut=3 covers u=48..63: only u=48 i.e. lg==0,i==0 valid)
            s[3][1] = -1e30f; s[3][2] = -1e30f; s[3][3] = -1e30f;
            if (lg) s[3][0] = -1e30f;
            // softmax over row t: 16 vals/lane x 4 lanes (lg) -> butterfly over lg
            float mx = -1e30f;
            #pragma unroll
            for (int ut = 0; ut < 4; ++ut)
                #pragma unroll
                for (int i = 0; i < 4; ++i) mx = fmaxf(mx, s[ut][i]);
            mx = fmaxf(mx, __shfl_xor(mx, 16));
            mx = fmaxf(mx, __shfl_xor(mx, 32));
            float sm = 0.f;
            #pragma unroll
            for (int ut = 0; ut < 4; ++ut)
                #pragma unroll
                for (int i = 0; i < 4; ++i) {
                    const float e = exp2f(s[ut][i] - mx);
                    s[ut][i] = e; sm += e;
                }
            sm += __shfl_xor(sm, 16);
            sm += __shfl_xor(sm, 32);
            const float inv = 1.f / sm;
            // P -> pt fragments (ku0 over qt[h,w], ku1 in pool), b64 swizzled writes
            #pragma unroll
            for (int ut = 0; ut < 4; ++ut) {
                uint2 pv;
                pv.x = pkrtz(s[ut][0] * inv, s[ut][1] * inv);
                pv.y = pkrtz(s[ut][2] * inv, s[ut][3] * inv);
                const int kg = (ut & 1) * 2 + (lg >> 1);
                const int base = (ut < 2) ? qfr : (PL + (w << 10));
                *(uint2*)(smem + base + SWU(l15, kg) * 16 + elb) = pv;
            }
            // PV (wave-local LDS, DS pipe in-order => no barrier)
            const half8 p0 = *(const half8*)(smem + qfr + swbase);
            const half8 p1 = *(const half8*)(smem + PL + (w << 10) + swbase);
            #pragma unroll
            for (int nd = 0; nd < 2; ++nd) {
                f4v o = {0.f, 0.f, 0.f, 0.f};
                o = MFMA(*(const half8*)(smem + VT + (((h * 2 + nd) * 2 + 0) << 10) + swbase), p0, o);
                o = MFMA(*(const half8*)(smem + VT + (((h * 2 + nd) * 2 + 1) << 10) + swbase), p1, o);
                uint2 ov;
                ov.x = pkrtz(o[0], o[1]);
                ov.y = pkrtz(o[2], o[3]);
                const int kg = nd * 2 + (lg >> 1);
                *(uint2*)(smem + qfr + SWU(l15, kg) * 16 + elb) = ov;
            }
            if (h < 2) {
                qa = qan;
                #pragma unroll
                for (int ut = 0; ut < 4; ++ut) kb[ut] = kbn[ut];
            }
        }
    }
    __syncthreads();

    // ============ Phase 3: transposed out-proj (Wo * O^T) + float4 stores ============
    {
        #pragma unroll
        for (int q = 0; q < 6; ++q) {
            const int p = w * 6 + q;
            const int nn = p >> 2, m = p & 3;
            f4v acc = {0.f, 0.f, 0.f, 0.f};
            #pragma unroll
            for (int ks = 0; ks < 3; ++ks) {
                const half8 wa = *(const half8*)(wo16 + (size_t)(nn * 16 + l15) * 96 + ks * 32 + lg * 8);
                const half8 ob = *(const half8*)(smem + QT + ((ks * 4 + m) << 10) + swbase);
                acc = MFMA(wa, ob, acc);
            }
            const int t = m * 16 + l15;
            if (t < 49) {
                const int tr = t / 7, tc = t - tr * 7;
                int r = wi7 + tr + 3; if (r >= 224) r -= 224;
                int c = wj7 + tc + 3; if (c >= 224) c -= 224;
                const float4 bo = *(const float4*)(bout + nn * 16 + lg * 4);
                float4 res;
                res.x = acc[0] + bo.x; res.y = acc[1] + bo.y;
                res.z = acc[2] + bo.z; res.w = acc[3] + bo.w;
                *(float4*)(out + ((size_t)((bb * 224 + r) * 224 + c)) * 96 + nn * 16 + lg * 4) = res;
            }
        }
    }
}

extern "C" void kernel_launch(void* const* d_in, const int* in_sizes, int n_in,
                              void* d_out, int out_size, void* d_ws, size_t ws_size,
                              hipStream_t stream) {
    const float* x          = (const float*)d_in[0];
    const float* w_qkv      = (const float*)d_in[1];
    const float* b_qkv      = (const float*)d_in[2];
    const float* w_out      = (const float*)d_in[3];
    const float* b_out      = (const float*)d_in[4];
    const float* bias_table = (const float*)d_in[5];
    const int*   rel_index  = (const int*)d_in[6];
    float* outp = (float*)d_out;

    // d_ws: wq16[27648]u16 | wo16[9216]u16 | bmat[3*64*64]f32 | bqs[288]f32  (124032 B)
    u16* wq16 = (u16*)d_ws;
    u16* wo16 = wq16 + 27648;
    float* bmat = (float*)((char*)d_ws + 73728);
    float* bqs  = (float*)((char*)d_ws + 122880);

    prep_kernel<<<dim3(194), dim3(256), 0, stream>>>(
        w_qkv, w_out, bias_table, rel_index, b_qkv, wq16, wo16, bmat, bqs);
    swin_kernel<<<dim3(8192), dim3(256), 0, stream>>>(
        x, wq16, wo16, bqs, b_out, bmat, outp);
}

// Round 7
// 219.164 us; speedup vs baseline: 1.2394x; 1.2394x over previous
//
#include <hip/hip_runtime.h>
#include <cstddef>

// Swin shifted-window attention, fused per-window MFMA kernel, fp16, v7.
// = v5's weight distribution (wave owns n = w, w+4, ... : each weight tile read
//   once per block, double-buffered) + v6's transposed Q/K projection (b64
//   swizzled scatter, no scalar LDS writes) + exp2 softmax + next-head prefetch.
// 8192 windows, one per 256-thread block (4 waves); LDS 40960 B -> 4 blocks/CU.

typedef _Float16 half8 __attribute__((ext_vector_type(8)));
typedef float f4v __attribute__((ext_vector_type(4)));
typedef unsigned short u16;
typedef unsigned int u32;

#define MFMA(A, B, C) __builtin_amdgcn_mfma_f32_16x16x32_f16((A), (B), (C), 0, 0, 0)

__device__ inline u16 f16b(float f) { return __builtin_bit_cast(u16, (_Float16)f); }
__device__ inline u32 pkrtz(float a, float b) {
    return __builtin_bit_cast(u32, __builtin_amdgcn_cvt_pkrtz(a, b));
}
// fragment-LDS unit swizzle: byte = frag*1024 + unit*16 + elem*2
__device__ inline int SWU(int a, int kg) {
    return (((a ^ (kg << 1) ^ ((a & 8) >> 1)) & 15) | (kg << 4));
}

// ---- prep: weights -> f16 (q rows pre-scaled by SCALE*log2e), bias matrix *log2e ----
__global__ void prep_kernel(const float* __restrict__ wqkv, const float* __restrict__ wout,
                            const float* __restrict__ btab, const int* __restrict__ ridx,
                            const float* __restrict__ bqkv,
                            u16* __restrict__ wq16, u16* __restrict__ wo16,
                            float* __restrict__ bmat, float* __restrict__ bqs)
{
    const int i = blockIdx.x * 256 + threadIdx.x;
    const float QS = 0.17677669529663688f * 1.4426950408889634f;  // 1/sqrt(32) * log2(e)
    if (i < 27648) {
        float f = wqkv[i];
        if (i < 9216) f *= QS;                 // q rows (0..95)
        wq16[i] = f16b(f);
    } else if (i < 36864) {
        wo16[i - 27648] = f16b(wout[i - 27648]);
    } else if (i < 49152) {
        const int j = i - 36864;               // [3][64][64]
        const int h = j >> 12, rem = j & 4095, r = rem >> 6, u = rem & 63;
        bmat[j] = (r < 49 && u < 49) ? btab[ridx[r * 49 + u] * 3 + h] * 1.4426950408889634f : 0.f;
    } else if (i < 49440) {
        const int j = i - 49152;
        float f = bqkv[j];
        if (j < 96) f *= QS;
        bqs[j] = f;
    }
}

// ---- main fused kernel ----
__global__ __launch_bounds__(256, 4)
void swin_kernel(const float* __restrict__ x,
                 const u16* __restrict__ wq16,
                 const u16* __restrict__ wo16,
                 const float* __restrict__ bqs,
                 const float* __restrict__ bout,
                 const float* __restrict__ bm,
                 float* __restrict__ out)
{
    // LDS map (40960 B -> 4 blocks/CU):
    //   QT [0,12288)      qt frag(h*4+m); reused per head as pt-ku0[m], then aot(h*4+m)
    //   KT [12288,24576)  kt frag(h*4+ut)
    //   VT [24576,36864)  vt frag((h*2+nd)*2+ku)
    //   PL [36864,40960)  pt-ku1, 1KB per wave
    __shared__ __attribute__((aligned(16))) char smem[40960];
    constexpr int QT = 0, KT = 12288, VT = 24576, PL = 36864;

    const int tid  = threadIdx.x;
    const int w    = tid >> 6;        // wave 0..3
    const int lane = tid & 63;
    const int l15  = lane & 15;
    const int lg   = lane >> 4;       // 0..3

    const int blk = blockIdx.x;
    const int bb  = blk >> 10;
    const int wi7 = ((blk >> 5) & 31) * 7;
    const int wj7 = (blk & 31) * 7;

    const int swbase = SWU(l15, lg) * 16;
    const int elb    = ((lg & 1) * 4) * 2;    // byte offset of el0 within unit

    // ============ Phase 1: QKV projection ============
    // X^T B-frags (dual-use as A-frags for the V path) for all 4 m-tiles.
    half8 xb[4][3];
    #pragma unroll
    for (int m = 0; m < 4; ++m) {
        const int t = m * 16 + l15;           // t>=49 reads junk (wrapped, in-bounds); masked later
        const int tr = t / 7, tc = t - tr * 7;
        int r = wi7 + tr + 3; if (r >= 224) r -= 224;
        int c = wj7 + tc + 3; if (c >= 224) c -= 224;
        const float* xrow = x + ((size_t)((bb * 224 + r) * 224 + c)) * 96 + lg * 8;
        #pragma unroll
        for (int ks = 0; ks < 3; ++ks) {
            const float4 f0 = *(const float4*)(xrow + ks * 32);
            const float4 f1 = *(const float4*)(xrow + ks * 32 + 4);
            uint4 pk;
            pk.x = pkrtz(f0.x, f0.y); pk.y = pkrtz(f0.z, f0.w);
            pk.z = pkrtz(f1.x, f1.y); pk.w = pkrtz(f1.z, f1.w);
            xb[m][ks] = __builtin_bit_cast(half8, pk);
        }
    }
    {
        const u16* wbase = wq16 + (size_t)l15 * 96 + lg * 8;
        half8 bcur[3], bnxt[3];
        int n = w;
        {
            const u16* p = wbase + n * 1536;
            bcur[0] = *(const half8*)(p);
            bcur[1] = *(const half8*)(p + 32);
            bcur[2] = *(const half8*)(p + 64);
        }
        while (true) {
            const int n2 = n + 4;
            if (n2 < 18) {
                const u16* p = wbase + n2 * 1536;
                bnxt[0] = *(const half8*)(p);
                bnxt[1] = *(const half8*)(p + 32);
                bnxt[2] = *(const half8*)(p + 64);
            }
            if (n < 12) {                      // q/k: transposed (A=W, B=X^T)
                const float4 b4 = *(const float4*)(bqs + n * 16 + lg * 4);
                const int kg = ((n & 1) << 1) + (lg >> 1);
                const int fr0 = (n < 6) ? (QT + (((n >> 1) * 4) << 10))
                                        : (KT + ((((n - 6) >> 1) * 4) << 10));
                #pragma unroll
                for (int m = 0; m < 4; ++m) {
                    f4v acc = {0.f, 0.f, 0.f, 0.f};
                    acc = MFMA(bcur[0], xb[m][0], acc);
                    acc = MFMA(bcur[1], xb[m][1], acc);
                    acc = MFMA(bcur[2], xb[m][2], acc);
                    uint2 pv;
                    pv.x = pkrtz(acc[0] + b4.x, acc[1] + b4.y);
                    pv.y = pkrtz(acc[2] + b4.z, acc[3] + b4.w);
                    *(uint2*)(smem + fr0 + (m << 10) + SWU(l15, kg) * 16 + elb) = pv;
                }
            } else {                           // v: direct (A=X, B=W^T)
                const float bv = bqs[n * 16 + l15];
                const int hh = (n - 12) >> 1, nd = n & 1;
                const int fr0 = VT + (((hh * 2 + nd) * 2) << 10);
                #pragma unroll
                for (int m = 0; m < 4; ++m) {
                    f4v acc = {0.f, 0.f, 0.f, 0.f};
                    acc = MFMA(xb[m][0], bcur[0], acc);
                    acc = MFMA(xb[m][1], bcur[1], acc);
                    acc = MFMA(xb[m][2], bcur[2], acc);
                    uint2 pv;
                    pv.x = pkrtz(acc[0] + bv, acc[1] + bv);
                    pv.y = pkrtz(acc[2] + bv, acc[3] + bv);
                    const int kg = ((m & 1) << 1) + (lg >> 1);
                    *(uint2*)(smem + fr0 + ((m >> 1) << 10) + SWU(l15, kg) * 16 + elb) = pv;
                }
            }
            if (n2 >= 18) break;
            bcur[0] = bnxt[0]; bcur[1] = bnxt[1]; bcur[2] = bnxt[2];
            n = n2;
        }
    }
    __syncthreads();

    // ============ Phase 2: attention, zero barriers (exp2 domain) ============
    {
        const int t = w * 16 + l15;
        half8 qa = *(const half8*)(smem + QT + ((0 * 4 + w) << 10) + swbase);
        half8 kb[4];
        #pragma unroll
        for (int ut = 0; ut < 4; ++ut)
            kb[ut] = *(const half8*)(smem + KT + ((0 * 4 + ut) << 10) + swbase);

        #pragma unroll
        for (int h = 0; h < 3; ++h) {
            const int qfr = QT + ((h * 4 + w) << 10);
            f4v s[4];
            #pragma unroll
            for (int ut = 0; ut < 4; ++ut) {
                f4v z = {0.f, 0.f, 0.f, 0.f};
                s[ut] = MFMA(kb[ut], qa, z);   // D[u-rows][t-cols], log2-scaled
            }
            // prefetch next head's operands (those frags are untouched this head)
            half8 qan; half8 kbn[4];
            if (h < 2) {
                qan = *(const half8*)(smem + QT + (((h + 1) * 4 + w) << 10) + swbase);
                #pragma unroll
                for (int ut = 0; ut < 4; ++ut)
                    kbn[ut] = *(const half8*)(smem + KT + (((h + 1) * 4 + ut) << 10) + swbase);
            }
            // + relative position bias (pre-scaled by log2e)
            const float* bp = bm + h * 4096 + t * 64 + lg * 4;
            #pragma unroll
            for (int ut = 0; ut < 4; ++ut) {
                const float4 bv = *(const float4*)(bp + ut * 16);
                s[ut][0] += bv.x; s[ut][1] += bv.y; s[ut][2] += bv.z; s[ut][3] += bv.w;
            }
            // mask u >= 49 (ut=3 covers u=48..63: only u=48 i.e. lg==0,i==0 valid)
            s[3][1] = -1e30f; s[3][2] = -1e30f; s[3][3] = -1e30f;
            if (lg) s[3][0] = -1e30f;
            // softmax over row t: 16 vals/lane x 4 lanes (lg) -> butterfly over lg
            float mx = -1e30f;
            #pragma unroll
            for (int ut = 0; ut < 4; ++ut)
                #pragma unroll
                for (int i = 0; i < 4; ++i) mx = fmaxf(mx, s[ut][i]);
            mx = fmaxf(mx, __shfl_xor(mx, 16));
            mx = fmaxf(mx, __shfl_xor(mx, 32));
            float sm = 0.f;
            #pragma unroll
            for (int ut = 0; ut < 4; ++ut)
                #pragma unroll
                for (int i = 0; i < 4; ++i) {
                    const float e = exp2f(s[ut][i] - mx);
                    s[ut][i] = e; sm += e;
                }
            sm += __shfl_xor(sm, 16);
            sm += __shfl_xor(sm, 32);
            const float inv = 1.f / sm;
            // P -> pt fragments (ku0 over qt[h,w], ku1 in pool), b64 swizzled writes
            #pragma unroll
            for (int ut = 0; ut < 4; ++ut) {
                uint2 pv;
                pv.x = pkrtz(s[ut][0] * inv, s[ut][1] * inv);
                pv.y = pkrtz(s[ut][2] * inv, s[ut][3] * inv);
                const int kg = (ut & 1) * 2 + (lg >> 1);
                const int base = (ut < 2) ? qfr : (PL + (w << 10));
                *(uint2*)(smem + base + SWU(l15, kg) * 16 + elb) = pv;
            }
            // PV (wave-local LDS, DS pipe in-order => no barrier)
            const half8 p0 = *(const half8*)(smem + qfr + swbase);
            const half8 p1 = *(const half8*)(smem + PL + (w << 10) + swbase);
            #pragma unroll
            for (int nd = 0; nd < 2; ++nd) {
                f4v o = {0.f, 0.f, 0.f, 0.f};
                o = MFMA(*(const half8*)(smem + VT + (((h * 2 + nd) * 2 + 0) << 10) + swbase), p0, o);
                o = MFMA(*(const half8*)(smem + VT + (((h * 2 + nd) * 2 + 1) << 10) + swbase), p1, o);
                uint2 ov;
                ov.x = pkrtz(o[0], o[1]);
                ov.y = pkrtz(o[2], o[3]);
                const int kg = nd * 2 + (lg >> 1);
                *(uint2*)(smem + qfr + SWU(l15, kg) * 16 + elb) = ov;
            }
            if (h < 2) {
                qa = qan;
                #pragma unroll
                for (int ut = 0; ut < 4; ++ut) kb[ut] = kbn[ut];
            }
        }
    }
    __syncthreads();

    // ============ Phase 3: transposed out-proj (Wo * O^T) + float4 stores ============
    {
        #pragma unroll
        for (int q = 0; q < 6; ++q) {
            const int p = w * 6 + q;
            const int nn = p >> 2, m = p & 3;
            f4v acc = {0.f, 0.f, 0.f, 0.f};
            #pragma unroll
            for (int ks = 0; ks < 3; ++ks) {
                const half8 wa = *(const half8*)(wo16 + (size_t)(nn * 16 + l15) * 96 + ks * 32 + lg * 8);
                const half8 ob = *(const half8*)(smem + QT + ((ks * 4 + m) << 10) + swbase);
                acc = MFMA(wa, ob, acc);
            }
            const int t = m * 16 + l15;
            if (t < 49) {
                const int tr = t / 7, tc = t - tr * 7;
                int r = wi7 + tr + 3; if (r >= 224) r -= 224;
                int c = wj7 + tc + 3; if (c >= 224) c -= 224;
                const float4 bo = *(const float4*)(bout + nn * 16 + lg * 4);
                float4 res;
                res.x = acc[0] + bo.x; res.y = acc[1] + bo.y;
                res.z = acc[2] + bo.z; res.w = acc[3] + bo.w;
                *(float4*)(out + ((size_t)((bb * 224 + r) * 224 + c)) * 96 + nn * 16 + lg * 4) = res;
            }
        }
    }
}

extern "C" void kernel_launch(void* const* d_in, const int* in_sizes, int n_in,
                              void* d_out, int out_size, void* d_ws, size_t ws_size,
                              hipStream_t stream) {
    const float* x          = (const float*)d_in[0];
    const float* w_qkv      = (const float*)d_in[1];
    const float* b_qkv      = (const float*)d_in[2];
    const float* w_out      = (const float*)d_in[3];
    const float* b_out      = (const float*)d_in[4];
    const float* bias_table = (const float*)d_in[5];
    const int*   rel_index  = (const int*)d_in[6];
    float* outp = (float*)d_out;

    // d_ws: wq16[27648]u16 | wo16[9216]u16 | bmat[3*64*64]f32 | bqs[288]f32  (124032 B)
    u16* wq16 = (u16*)d_ws;
    u16* wo16 = wq16 + 27648;
    float* bmat = (float*)((char*)d_ws + 73728);
    float* bqs  = (float*)((char*)d_ws + 122880);

    prep_kernel<<<dim3(194), dim3(256), 0, stream>>>(
        w_qkv, w_out, bias_table, rel_index, b_qkv, wq16, wo16, bmat, bqs);
    swin_kernel<<<dim3(8192), dim3(256), 0, stream>>>(
        x, wq16, wo16, bqs, b_out, bmat, outp);
}

// Round 8
// 208.746 us; speedup vs baseline: 1.3013x; 1.0499x over previous
//
#include <hip/hip_runtime.h>
#include <cstddef>

// Swin shifted-window attention, fused per-window MFMA kernel, fp16, v8.
// v7 + (a) ONE barrier total: phase-3 redistributed so wave w owns m-tile w ->
// ao frags are wave-private (qt[h][w] slots), no post-attention barriers;
// (b) software-pipelined head loop: scores(h+1) MFMA issued between softmax(h)
// and PV(h); (c) rel-pos bias pre-laid-out as MFMA C-operand fragments with
// -1e30 mask baked in (removes bias-add + mask VALU); (d) phase-3 ob/address hoist.
// 8192 windows, one per 256-thread block (4 waves); LDS 40960 B -> 4 blocks/CU.

typedef _Float16 half8 __attribute__((ext_vector_type(8)));
typedef float f4v __attribute__((ext_vector_type(4)));
typedef unsigned short u16;
typedef unsigned int u32;

#define MFMA(A, B, C) __builtin_amdgcn_mfma_f32_16x16x32_f16((A), (B), (C), 0, 0, 0)

__device__ inline u16 f16b(float f) { return __builtin_bit_cast(u16, (_Float16)f); }
__device__ inline u32 pkrtz(float a, float b) {
    return __builtin_bit_cast(u32, __builtin_amdgcn_cvt_pkrtz(a, b));
}
// fragment-LDS unit swizzle: byte = frag*1024 + unit*16 + elem*2
__device__ inline int SWU(int a, int kg) {
    return (((a ^ (kg << 1) ^ ((a & 8) >> 1)) & 15) | (kg << 4));
}

// ---- prep: weights -> f16 (q pre-scaled by SCALE*log2e); bias -> C-fragment layout ----
__global__ void prep_kernel(const float* __restrict__ wqkv, const float* __restrict__ wout,
                            const float* __restrict__ btab, const int* __restrict__ ridx,
                            const float* __restrict__ bqkv,
                            u16* __restrict__ wq16, u16* __restrict__ wo16,
                            float* __restrict__ bmf, float* __restrict__ bqs)
{
    const int i = blockIdx.x * 256 + threadIdx.x;
    const float LOG2E = 1.4426950408889634f;
    const float QS = 0.17677669529663688f * LOG2E;   // 1/sqrt(32) * log2(e)
    if (i < 27648) {
        float f = wqkv[i];
        if (i < 9216) f *= QS;                 // q rows
        wq16[i] = f16b(f);
    } else if (i < 36864) {
        wo16[i - 27648] = f16b(wout[i - 27648]);
    } else if (i < 49152) {
        // bmf: C-operand fragments, j = ((h*4+ut)*4+w)*256 + lane*4 + i
        // lane (l15,lg), reg i holds D[u = ut*16+lg*4+i][t = w*16+l15]
        const int j  = i - 36864;
        const int fi = j & 3, ln = (j >> 2) & 63, fw = (j >> 8) & 3;
        const int fut = (j >> 10) & 3, fh = j >> 12;
        const int u  = fut * 16 + (ln >> 4) * 4 + fi;
        const int tt = fw * 16 + (ln & 15);
        float v;
        if (u >= 49)      v = -1e30f;                                   // mask baked in
        else if (tt >= 49) v = 0.f;                                     // junk rows, don't care
        else               v = btab[ridx[tt * 49 + u] * 3 + fh] * LOG2E;
        bmf[j] = v;
    } else if (i < 49440) {
        const int j = i - 49152;
        float f = bqkv[j];
        if (j < 96) f *= QS;
        bqs[j] = f;
    }
}

// ---- main fused kernel ----
__global__ __launch_bounds__(256, 4)
void swin_kernel(const float* __restrict__ x,
                 const u16* __restrict__ wq16,
                 const u16* __restrict__ wo16,
                 const float* __restrict__ bqs,
                 const float* __restrict__ bout,
                 const float* __restrict__ bmf,
                 float* __restrict__ out)
{
    // LDS map (40960 B -> 4 blocks/CU):
    //   QT [0,12288)      qt frag(h*4+m); per head: P-ku0 then ao (all wave-private in slot [.][w])
    //   KT [12288,24576)  kt frag(h*4+ut)  (read-only after barrier)
    //   VT [24576,36864)  vt frag((h*2+nd)*2+ku)  (read-only after barrier)
    //   PL [36864,40960)  P-ku1, 1KB per wave (wave-private)
    __shared__ __attribute__((aligned(16))) char smem[40960];
    constexpr int QT = 0, KT = 12288, VT = 24576, PL = 36864;

    const int tid  = threadIdx.x;
    const int w    = tid >> 6;        // wave 0..3 = token m-tile owned
    const int lane = tid & 63;
    const int l15  = lane & 15;
    const int lg   = lane >> 4;       // 0..3

    const int blk = blockIdx.x;
    const int bb  = blk >> 10;
    const int wi7 = ((blk >> 5) & 31) * 7;
    const int wj7 = (blk & 31) * 7;

    const int swbase = SWU(l15, lg) * 16;
    const int elb    = ((lg & 1) * 4) * 2;    // byte offset of el0 within unit

    // ============ Phase 1: QKV projection (v7, unchanged) ============
    half8 xb[4][3];
    #pragma unroll
    for (int m = 0; m < 4; ++m) {
        const int t = m * 16 + l15;           // t>=49 reads junk (wrapped, in-bounds); masked later
        const int tr = t / 7, tc = t - tr * 7;
        int r = wi7 + tr + 3; if (r >= 224) r -= 224;
        int c = wj7 + tc + 3; if (c >= 224) c -= 224;
        const float* xrow = x + ((size_t)((bb * 224 + r) * 224 + c)) * 96 + lg * 8;
        #pragma unroll
        for (int ks = 0; ks < 3; ++ks) {
            const float4 f0 = *(const float4*)(xrow + ks * 32);
            const float4 f1 = *(const float4*)(xrow + ks * 32 + 4);
            uint4 pk;
            pk.x = pkrtz(f0.x, f0.y); pk.y = pkrtz(f0.z, f0.w);
            pk.z = pkrtz(f1.x, f1.y); pk.w = pkrtz(f1.z, f1.w);
            xb[m][ks] = __builtin_bit_cast(half8, pk);
        }
    }
    {
        const u16* wbase = wq16 + (size_t)l15 * 96 + lg * 8;
        half8 bcur[3], bnxt[3];
        int n = w;
        {
            const u16* p = wbase + n * 1536;
            bcur[0] = *(const half8*)(p);
            bcur[1] = *(const half8*)(p + 32);
            bcur[2] = *(const half8*)(p + 64);
        }
        while (true) {
            const int n2 = n + 4;
            if (n2 < 18) {
                const u16* p = wbase + n2 * 1536;
                bnxt[0] = *(const half8*)(p);
                bnxt[1] = *(const half8*)(p + 32);
                bnxt[2] = *(const half8*)(p + 64);
            }
            if (n < 12) {                      // q/k: transposed (A=W, B=X^T)
                const float4 b4 = *(const float4*)(bqs + n * 16 + lg * 4);
                const int kg = ((n & 1) << 1) + (lg >> 1);
                const int fr0 = (n < 6) ? (QT + (((n >> 1) * 4) << 10))
                                        : (KT + ((((n - 6) >> 1) * 4) << 10));
                #pragma unroll
                for (int m = 0; m < 4; ++m) {
                    f4v acc = {0.f, 0.f, 0.f, 0.f};
                    acc = MFMA(bcur[0], xb[m][0], acc);
                    acc = MFMA(bcur[1], xb[m][1], acc);
                    acc = MFMA(bcur[2], xb[m][2], acc);
                    uint2 pv;
                    pv.x = pkrtz(acc[0] + b4.x, acc[1] + b4.y);
                    pv.y = pkrtz(acc[2] + b4.z, acc[3] + b4.w);
                    *(uint2*)(smem + fr0 + (m << 10) + SWU(l15, kg) * 16 + elb) = pv;
                }
            } else {                           // v: direct (A=X, B=W^T)
                const float bv = bqs[n * 16 + l15];
                const int hh = (n - 12) >> 1, nd = n & 1;
                const int fr0 = VT + (((hh * 2 + nd) * 2) << 10);
                #pragma unroll
                for (int m = 0; m < 4; ++m) {
                    f4v acc = {0.f, 0.f, 0.f, 0.f};
                    acc = MFMA(xb[m][0], bcur[0], acc);
                    acc = MFMA(xb[m][1], bcur[1], acc);
                    acc = MFMA(xb[m][2], bcur[2], acc);
                    uint2 pv;
                    pv.x = pkrtz(acc[0] + bv, acc[1] + bv);
                    pv.y = pkrtz(acc[2] + bv, acc[3] + bv);
                    const int kg = ((m & 1) << 1) + (lg >> 1);
                    *(uint2*)(smem + fr0 + ((m >> 1) << 10) + SWU(l15, kg) * 16 + elb) = pv;
                }
            }
            if (n2 >= 18) break;
            bcur[0] = bnxt[0]; bcur[1] = bnxt[1]; bcur[2] = bnxt[2];
            n = n2;
        }
    }
    __syncthreads();      // the ONLY barrier

    // ============ Phase 2: attention, software-pipelined, zero barriers ============
    {
        const int plb = PL + (w << 10);
        half8 qaC, qaN;
        half8 kb[2][4];
        f4v   s[2][4];
        f4v   bC[4];

        // preamble: head 0
        qaC = *(const half8*)(smem + QT + ((0 * 4 + w) << 10) + swbase);
        #pragma unroll
        for (int ut = 0; ut < 4; ++ut)
            kb[0][ut] = *(const half8*)(smem + KT + ((0 * 4 + ut) << 10) + swbase);
        {
            const float* bb0 = bmf + w * 256 + lane * 4;
            #pragma unroll
            for (int ut = 0; ut < 4; ++ut) bC[ut] = *(const f4v*)(bb0 + ut * 1024);
        }
        #pragma unroll
        for (int ut = 0; ut < 4; ++ut)
            s[0][ut] = MFMA(kb[0][ut], qaC, bC[ut]);     // bias+mask folded into C

        #pragma unroll
        for (int h = 0; h < 3; ++h) {
            const int cur = h & 1, nxt = cur ^ 1;
            const int qfr = QT + ((h * 4 + w) << 10);
            // prefetch next head operands (DS + global, in flight under softmax)
            if (h < 2) {
                qaN = *(const half8*)(smem + QT + (((h + 1) * 4 + w) << 10) + swbase);
                #pragma unroll
                for (int ut = 0; ut < 4; ++ut)
                    kb[nxt][ut] = *(const half8*)(smem + KT + (((h + 1) * 4 + ut) << 10) + swbase);
                const float* bbn = bmf + (h + 1) * 4096 + w * 256 + lane * 4;
                #pragma unroll
                for (int ut = 0; ut < 4; ++ut) bC[ut] = *(const f4v*)(bbn + ut * 1024);
            }
            // softmax on s[cur] (log2 domain; mask already applied via C)
            float mx = fmaxf(fmaxf(s[cur][0][0], s[cur][0][1]), fmaxf(s[cur][0][2], s[cur][0][3]));
            #pragma unroll
            for (int ut = 1; ut < 4; ++ut) {
                mx = fmaxf(mx, fmaxf(fmaxf(s[cur][ut][0], s[cur][ut][1]),
                                     fmaxf(s[cur][ut][2], s[cur][ut][3])));
            }
            mx = fmaxf(mx, __shfl_xor(mx, 16));
            mx = fmaxf(mx, __shfl_xor(mx, 32));
            float sm = 0.f;
            #pragma unroll
            for (int ut = 0; ut < 4; ++ut)
                #pragma unroll
                for (int i = 0; i < 4; ++i) {
                    const float e = exp2f(s[cur][ut][i] - mx);
                    s[cur][ut][i] = e; sm += e;
                }
            sm += __shfl_xor(sm, 16);
            sm += __shfl_xor(sm, 32);
            const float inv = 1.f / sm;
            // pack + write P (ku0 -> qt[h][w] slot, ku1 -> PL[w]; both wave-private)
            #pragma unroll
            for (int ut = 0; ut < 4; ++ut) {
                uint2 pv;
                pv.x = pkrtz(s[cur][ut][0] * inv, s[cur][ut][1] * inv);
                pv.y = pkrtz(s[cur][ut][2] * inv, s[cur][ut][3] * inv);
                const int kg = (ut & 1) * 2 + (lg >> 1);
                const int base = (ut < 2) ? qfr : plb;
                *(uint2*)(smem + base + SWU(l15, kg) * 16 + elb) = pv;
            }
            // V reads issue (in flight under scores(h+1))
            const half8 vb00 = *(const half8*)(smem + VT + (((h * 2 + 0) * 2 + 0) << 10) + swbase);
            const half8 vb01 = *(const half8*)(smem + VT + (((h * 2 + 0) * 2 + 1) << 10) + swbase);
            const half8 vb10 = *(const half8*)(smem + VT + (((h * 2 + 1) * 2 + 0) << 10) + swbase);
            const half8 vb11 = *(const half8*)(smem + VT + (((h * 2 + 1) * 2 + 1) << 10) + swbase);
            // scores(h+1): MFMA on prefetched operands, overlaps P/V DS traffic
            if (h < 2) {
                #pragma unroll
                for (int ut = 0; ut < 4; ++ut)
                    s[nxt][ut] = MFMA(kb[nxt][ut], qaN, bC[ut]);
            }
            // P readback + PV
            const half8 p0 = *(const half8*)(smem + qfr + swbase);
            const half8 p1 = *(const half8*)(smem + plb + swbase);
            #pragma unroll
            for (int nd = 0; nd < 2; ++nd) {
                f4v o = {0.f, 0.f, 0.f, 0.f};
                o = MFMA(nd ? vb10 : vb00, p0, o);
                o = MFMA(nd ? vb11 : vb01, p1, o);
                // ao(h,nd) -> qt[h][w] slot (over dead P-ku0; in-order DS, wave-private)
                uint2 ov;
                ov.x = pkrtz(o[0], o[1]);
                ov.y = pkrtz(o[2], o[3]);
                *(uint2*)(smem + qfr + SWU(l15, nd * 2 + (lg >> 1)) * 16 + elb) = ov;
            }
        }
    }
    // NO barrier: phase 3 reads only this wave's own qt slots

    // ============ Phase 3: transposed out-proj, wave w owns m-tile w ============
    {
        const half8 ob0 = *(const half8*)(smem + QT + ((0 * 4 + w) << 10) + swbase);
        const half8 ob1 = *(const half8*)(smem + QT + ((1 * 4 + w) << 10) + swbase);
        const half8 ob2 = *(const half8*)(smem + QT + ((2 * 4 + w) << 10) + swbase);
        const int t = w * 16 + l15;
        float* obase = nullptr;
        if (t < 49) {
            const int tr = t / 7, tc = t - tr * 7;
            int r = wi7 + tr + 3; if (r >= 224) r -= 224;
            int c = wj7 + tc + 3; if (c >= 224) c -= 224;
            obase = out + ((size_t)((bb * 224 + r) * 224 + c)) * 96;
        }
        #pragma unroll
        for (int nn = 0; nn < 6; ++nn) {
            const u16* wp = wo16 + (size_t)(nn * 16 + l15) * 96 + lg * 8;
            f4v acc = {0.f, 0.f, 0.f, 0.f};
            acc = MFMA(*(const half8*)(wp),      ob0, acc);
            acc = MFMA(*(const half8*)(wp + 32), ob1, acc);
            acc = MFMA(*(const half8*)(wp + 64), ob2, acc);
            if (obase) {
                const float4 bo = *(const float4*)(bout + nn * 16 + lg * 4);
                float4 res;
                res.x = acc[0] + bo.x; res.y = acc[1] + bo.y;
                res.z = acc[2] + bo.z; res.w = acc[3] + bo.w;
                *(float4*)(obase + nn * 16 + lg * 4) = res;
            }
        }
    }
}

extern "C" void kernel_launch(void* const* d_in, const int* in_sizes, int n_in,
                              void* d_out, int out_size, void* d_ws, size_t ws_size,
                              hipStream_t stream) {
    const float* x          = (const float*)d_in[0];
    const float* w_qkv      = (const float*)d_in[1];
    const float* b_qkv      = (const float*)d_in[2];
    const float* w_out      = (const float*)d_in[3];
    const float* b_out      = (const float*)d_in[4];
    const float* bias_table = (const float*)d_in[5];
    const int*   rel_index  = (const int*)d_in[6];
    float* outp = (float*)d_out;

    // d_ws: wq16[27648]u16 | wo16[9216]u16 | bmf[3*4*4*256]f32 | bqs[288]f32  (124032 B)
    u16* wq16 = (u16*)d_ws;
    u16* wo16 = wq16 + 27648;
    float* bmf = (float*)((char*)d_ws + 73728);
    float* bqs = (float*)((char*)d_ws + 122880);

    prep_kernel<<<dim3(194), dim3(256), 0, stream>>>(
        w_qkv, w_out, bias_table, rel_index, b_qkv, wq16, wo16, bmf, bqs);
    swin_kernel<<<dim3(8192), dim3(256), 0, stream>>>(
        x, wq16, wo16, bqs, b_out, bmf, outp);
}